// Round 1
// baseline (495.362 us; speedup 1.0000x reference)
//
#include <hip/hip_runtime.h>

#define NN 50000
#define DD 64
#define BB 32
#define TILE 256
#define NPB ((NN + TILE - 1) / TILE)   // 196 blocks per batch

// Pass 1 (thread-per-row): lane owns one full 64-float row.
// 16 independent dwordx4 loads in ONE predicated region -> deep MLP,
// no shuffles/LDS on the load path. a_src is uniform -> scalar regs.
// p written straight to out; block partial sums to unique d_ws slots.
__global__ __launch_bounds__(256) void attn_pass1(
    const float* __restrict__ x, const float* __restrict__ a,
    const int* __restrict__ node_index, const int* __restrict__ adj,
    float* __restrict__ out, float* __restrict__ pbs /* [BB][NPB] */)
{
    const int tid = threadIdx.x;
    const int b = blockIdx.y;
    const int r = blockIdx.x * TILE + tid;
    const int node = *node_index;

    __shared__ float sh_tgt;
    __shared__ float sh_red[4];

    // my row's mask — coalesced global dword, issued ASAP
    int msk = 0;
    if (r < NN) msk = adj[r];

    // target score: dot(x[b,node,:], a[:64]) — wave 0, L2-hot after first block
    if (tid < 64) {
        float v = x[(size_t)b * NN * DD + (size_t)node * DD + tid] * a[tid];
        #pragma unroll
        for (int o = 32; o >= 1; o >>= 1) v += __shfl_xor(v, o, 64);
        if (tid == 0) sh_tgt = v;
    }

    // a_src: uniform address per j -> compiler emits s_load; FMA reads SGPR
    float av[DD];
    #pragma unroll
    for (int j = 0; j < DD; j++) av[j] = a[DD + j];

    __syncthreads();
    const float tgt = sh_tgt;

    float p = 0.f;
    if (msk > 0) {
        const float4* __restrict__ xr =
            (const float4*)(x + (size_t)b * NN * DD + (size_t)r * DD);
        // 16 independent 16B loads, all in flight together
        float4 v[16];
        #pragma unroll
        for (int k = 0; k < 16; k++) v[k] = xr[k];
        // 4 accumulators -> 16-deep chains instead of one 64-deep chain
        float s0 = 0.f, s1 = 0.f, s2 = 0.f, s3 = 0.f;
        #pragma unroll
        for (int k = 0; k < 16; k++) {
            s0 += v[k].x * av[4 * k + 0];
            s1 += v[k].y * av[4 * k + 1];
            s2 += v[k].z * av[4 * k + 2];
            s3 += v[k].w * av[4 * k + 3];
        }
        const float z = tgt + ((s0 + s1) + (s2 + s3));
        const float e = (z > 0.f) ? z : 0.01f * z;
        p = __expf(e);
    }
    if (r < NN) out[(size_t)b * NN + r] = p;   // coalesced, unnormalized

    // block sum of p (all 256 lanes hold a value; masked rows hold 0)
    float loc = p;
    #pragma unroll
    for (int o = 32; o >= 1; o >>= 1) loc += __shfl_xor(loc, o, 64);
    if ((tid & 63) == 0) sh_red[tid >> 6] = loc;
    __syncthreads();
    if (tid == 0)
        pbs[b * NPB + blockIdx.x] = sh_red[0] + sh_red[1] + sh_red[2] + sh_red[3];
}

// Pass 2: out[b,n] /= sum_b.  Each block reduces its batch's 196 partials
// (L2-hot, ~0.8 KB) then scales its float4 span.
__global__ __launch_bounds__(256) void attn_pass2(
    float* __restrict__ out, const float* __restrict__ pbs)
{
    const int tid = threadIdx.x;
    const int b = blockIdx.y;
    __shared__ float sh[4];

    float v = (tid < NPB) ? pbs[b * NPB + tid] : 0.f;
    #pragma unroll
    for (int o = 32; o >= 1; o >>= 1) v += __shfl_xor(v, o, 64);
    if ((tid & 63) == 0) sh[tid >> 6] = v;
    __syncthreads();
    const float inv = 1.0f / (sh[0] + sh[1] + sh[2] + sh[3]);

    const int N4 = NN / 4;  // 12500
    const int f = blockIdx.x * blockDim.x + tid;
    if (f < N4) {
        float4* p = (float4*)out + (size_t)b * N4 + f;
        float4 w = *p;
        w.x *= inv; w.y *= inv; w.z *= inv; w.w *= inv;
        *p = w;
    }
}

extern "C" void kernel_launch(void* const* d_in, const int* in_sizes, int n_in,
                              void* d_out, int out_size, void* d_ws, size_t ws_size,
                              hipStream_t stream) {
    const float* x = (const float*)d_in[0];         // (B, N, D) fp32
    const float* a = (const float*)d_in[1];         // (2D, 1) fp32
    const int* node_index = (const int*)d_in[2];    // scalar
    const int* adj = (const int*)d_in[3];           // (N,) int32
    float* out = (float*)d_out;                     // (B, N) fp32
    float* pbs = (float*)d_ws;                      // [32][196] partials, all written

    dim3 g1(NPB, BB);                        // (196, 32)
    attn_pass1<<<g1, 256, 0, stream>>>(x, a, node_index, adj, out, pbs);

    dim3 g2((NN / 4 + 255) / 256, BB);       // (49, 32)
    attn_pass2<<<g2, 256, 0, stream>>>(out, pbs);
}